// Round 12
// baseline (1751.605 us; speedup 1.0000x reference)
//
#include <hip/hip_runtime.h>

typedef unsigned short u16;
typedef unsigned int   u32;
typedef unsigned long long u64;

typedef short bf16x8 __attribute__((ext_vector_type(8)));
typedef float f32x4  __attribute__((ext_vector_type(4)));

#define A_SYN  0.90483741803595957f   // exp(-0.5/5)
#define A_VM   0.95122942450071400f   // exp(-0.5/10)
#define BETA   0.04877057549928600f   // 1 - A_VM
#define C_RATE 0.09754115099857200f   // (1/DT)*(1-alpha_out) = 2*BETA
#define R_H    0.04419417382415922f   // 1*1*10/5 * sqrt(1/2048)
#define R_IN   4.41941738241592200f   // 10*1*10 * sqrt(1/512)
#define R_OUT  2.20970869120796080f   // 100 * sqrt(1/2048)

__device__ __forceinline__ u16 f2b(float f){
  u32 x = __float_as_uint(f);
  return (u16)((x + 0x7FFFu + ((x >> 16) & 1u)) >> 16);   // RNE f32->bf16
}
__device__ __forceinline__ float b2f(u16 u){ return __uint_as_float(((u32)u) << 16); }

// ---------------- prep: row sums of x -> sbeta[m]; convert x to bf16 ----------------
__global__ __launch_bounds__(256) void prep_x(const float* __restrict__ x,
                                              u16* __restrict__ xb,
                                              float* __restrict__ sbeta){
  const int m = blockIdx.x;
  const int tid = threadIdx.x;
  const float4 xv = ((const float4*)(x + (size_t)m * 1024))[tid];
  float s = xv.x + xv.y + xv.z + xv.w;
  #pragma unroll
  for (int off = 32; off > 0; off >>= 1) s += __shfl_down(s, off, 64);
  __shared__ float ps[4];
  if ((tid & 63) == 0) ps[tid >> 6] = s;
  __syncthreads();
  float tot = ps[0] + ps[1] + ps[2] + ps[3];
  float sc = fminf(30.0f / (tot + 1.0f), 10.0f) * (R_IN * BETA);
  if (tid == 0) sbeta[m] = sc;
  ushort4 o; o.x = f2b(xv.x); o.y = f2b(xv.y); o.z = f2b(xv.z); o.w = f2b(xv.w);
  ((ushort4*)(xb + (size_t)m * 1024))[tid] = o;
}

// ---------------- detect bool layout: int32 words (0/1) vs packed bytes ----------------
__global__ void detect_layout(const u32* __restrict__ khw, u32* __restrict__ flag){
  u32 bad = 0;
  #pragma unroll
  for (int i = 0; i < 4; ++i){ u32 v = khw[threadIdx.x + i * 256]; bad |= (v > 1u) ? 1u : 0u; }
  if (bad) *flag = 1u;
}

// ---------------- prep: kernel_in -> Bt[n][k] bf16 (transposed) ----------------
__global__ __launch_bounds__(256) void prep_bt(const int* __restrict__ ki,
                                               const u32* __restrict__ flag,
                                               u16* __restrict__ Bt){
  __shared__ u16 tile[64][65];
  const int k0 = blockIdx.x * 64, n0 = blockIdx.y * 64;
  const int tr = threadIdx.x >> 6, tc = threadIdx.x & 63;
  const bool bm = (*flag) != 0;
  const unsigned char* kib = (const unsigned char*)ki;
  #pragma unroll 4
  for (int r = 0; r < 16; ++r){
    int row = r * 4 + tr;
    size_t idx = (size_t)(k0 + row) * 4096 + (n0 + tc);
    int v = bm ? (int)kib[idx] : ki[idx];
    tile[row][tc] = v ? (u16)0x3F80 : (u16)0;
  }
  __syncthreads();
  #pragma unroll 4
  for (int r = 0; r < 16; ++r){
    int row = r * 4 + tr;
    Bt[(size_t)(n0 + row) * 1024 + (k0 + tc)] = tile[tc][row];
  }
}

// ---------------- prep: kernel_h -> khT bit-packed [w][n], bit j = kh[w*64+j][n] ----------------
__global__ __launch_bounds__(256) void prep_kh(const int* __restrict__ kh,
                                               const u32* __restrict__ flag,
                                               u64* __restrict__ khT){
  const int n = blockIdx.x * 256 + threadIdx.x;
  const int w = blockIdx.y;
  const bool bm = (*flag) != 0;
  const unsigned char* khb = (const unsigned char*)kh;
  u64 bits = 0;
  #pragma unroll 8
  for (int j = 0; j < 64; ++j){
    size_t idx = (size_t)(w * 64 + j) * 4096 + n;
    int v = bm ? (int)khb[idx] : kh[idx];
    bits |= (u64)(v & 1) << j;
  }
  khT[(size_t)w * 4096 + n] = bits;
}

// ---------------- prep: kernel_h -> khW u16 table: khW[p][c] bit j = kh[p][j*256+c] ----------------
// Row p=4096 is all-zero (padding row for branch-free event slots).
__global__ __launch_bounds__(256) void prep_khW(const int* __restrict__ kh,
                                                const u32* __restrict__ flag,
                                                u16* __restrict__ khW){
  const int p = blockIdx.x;
  const int c = threadIdx.x;
  if (p >= 4096){ khW[(size_t)p * 256 + c] = 0; return; }
  const bool bm = (*flag) != 0;
  u32 b = 0;
  if (bm){
    const unsigned char* r = (const unsigned char*)kh + (size_t)p * 4096;
    #pragma unroll
    for (int j = 0; j < 16; ++j) b |= (u32)(r[j * 256 + c] & 1) << j;
  } else {
    const int* r = kh + (size_t)p * 4096;
    #pragma unroll
    for (int j = 0; j < 16; ++j) b |= (u32)(r[j * 256 + c] & 1) << j;
  }
  khW[(size_t)p * 256 + c] = (u16)b;
}

// ---------------- bf16 GEMM with XCD swizzle ----------------
__global__ __launch_bounds__(256) void gemm_iin(const u16* __restrict__ A,
                                                const u16* __restrict__ Bm,
                                                const float* __restrict__ sbeta,
                                                u16* __restrict__ C){
  __shared__ u16 As[128 * 32];
  __shared__ u16 Bs[128 * 32];
  const int tid = threadIdx.x;
  const int lane = tid & 63, w = tid >> 6;
  const int wm = w >> 1, wn = w & 1;
  const int id = blockIdx.y * 128 + blockIdx.x;
  const int swz = (id & 7) * 512 + (id >> 3);
  const int m0 = (swz & 127) * 128, n0 = (swz >> 7) * 128;
  const int l15 = lane & 15, lq = lane >> 4;
  const int K = 1024;

  f32x4 acc[4][4];
  #pragma unroll
  for (int i = 0; i < 4; ++i)
    #pragma unroll
    for (int j = 0; j < 4; ++j) acc[i][j] = (f32x4){0.f, 0.f, 0.f, 0.f};

  const u16* ag = A  + (size_t)(m0 + (tid >> 2)) * K + (tid & 3) * 8;
  const u16* bg = Bm + (size_t)(n0 + (tid >> 2)) * K + (tid & 3) * 8;

  for (int kt = 0; kt < 32; ++kt){
    __builtin_amdgcn_global_load_lds((const __attribute__((address_space(1))) u32*)(ag + kt * 32),
        (__attribute__((address_space(3))) u32*)(As + tid * 8), 16, 0, 0);
    __builtin_amdgcn_global_load_lds((const __attribute__((address_space(1))) u32*)(ag + (size_t)64 * K + kt * 32),
        (__attribute__((address_space(3))) u32*)(As + 2048 + tid * 8), 16, 0, 0);
    __builtin_amdgcn_global_load_lds((const __attribute__((address_space(1))) u32*)(bg + kt * 32),
        (__attribute__((address_space(3))) u32*)(Bs + tid * 8), 16, 0, 0);
    __builtin_amdgcn_global_load_lds((const __attribute__((address_space(1))) u32*)(bg + (size_t)64 * K + kt * 32),
        (__attribute__((address_space(3))) u32*)(Bs + 2048 + tid * 8), 16, 0, 0);
    __syncthreads();
    bf16x8 af[4], bf[4];
    #pragma unroll
    for (int f = 0; f < 4; ++f){
      af[f] = *(const bf16x8*)(As + (wm * 64 + f * 16 + l15) * 32 + lq * 8);
      bf[f] = *(const bf16x8*)(Bs + (wn * 64 + f * 16 + l15) * 32 + lq * 8);
    }
    #pragma unroll
    for (int fm = 0; fm < 4; ++fm)
      #pragma unroll
      for (int fn = 0; fn < 4; ++fn)
        acc[fm][fn] = __builtin_amdgcn_mfma_f32_16x16x32_bf16(af[fm], bf[fn], acc[fm][fn], 0, 0, 0);
    __syncthreads();
  }

  float sb[4][4];
  #pragma unroll
  for (int fm = 0; fm < 4; ++fm)
    #pragma unroll
    for (int i = 0; i < 4; ++i)
      sb[fm][i] = sbeta[m0 + wm * 64 + fm * 16 + lq * 4 + i];
  #pragma unroll
  for (int fm = 0; fm < 4; ++fm)
    #pragma unroll
    for (int fn = 0; fn < 4; ++fn)
      #pragma unroll
      for (int i = 0; i < 4; ++i){
        size_t row = (size_t)(m0 + wm * 64 + fm * 16 + lq * 4 + i);
        int col = n0 + wn * 64 + fn * 16 + l15;
        C[row * 4096 + col] = f2b(acc[fm][fn][i] * sb[fm][i]);
      }
}

// ===== SNN scan: 256 threads / 4 waves, 16 neurons/thread (n = j*256 + tid), SALU-lean =====
// event u32: bits0-12 p (4096 = zero pad row) | bit13 neg. Always-4 padded slots.

struct ScanLds {
  unsigned char cntb[2][4];                      // per-wave flip count (0xFF = dense)
  u32 seg[2][4][4] __attribute__((aligned(16)));
  u64 fpos[2][64], fneg[2][64];                  // [j*4+w], dense path only
};

__device__ __forceinline__ void produce(
    int lane, int w, int buf,
    const u64 (&bsp)[16], const u64 (&bfl)[16], bool wany, ScanLds* L)
{
  if (lane == 0){
    u32 cb = 0;
    if (wany){
      int cnt = 0;
      #pragma unroll
      for (int j = 0; j < 16; ++j) cnt += __popcll(bfl[j]);
      if (cnt <= 4){
        cb = (u32)cnt;
        u32 evs[4] = {4096u, 4096u, 4096u, 4096u};   // pad -> zero row
        int idx = 0;
        #pragma unroll 1
        for (int j = 0; j < 16; ++j){
          u64 m = bfl[j];
          while (m){
            int bit = (int)__builtin_ctzll(m); m &= m - 1;
            u32 p = (u32)(j * 256 + w * 64 + bit);
            u32 rising = (u32)((bsp[j] >> bit) & 1ull);
            u32 neg = (j < 8) ? (rising ^ 1u) : rising;   // dale: exc iff p<2048 iff j<8
            evs[idx++] = p | (neg << 13);
          }
        }
        *(uint4*)&L->seg[buf][w][0] = make_uint4(evs[0], evs[1], evs[2], evs[3]);
      } else {
        cb = 0xFFu;
        #pragma unroll
        for (int j = 0; j < 16; ++j){
          L->fpos[buf][j * 4 + w] = bfl[j] & bsp[j];
          L->fneg[buf][j * 4 + w] = bfl[j] & ~bsp[j];
        }
      }
    }
    L->cntb[buf][w] = (unsigned char)cb;
  }
}

__device__ __forceinline__ void consume(
    int tid, int buf,
    const u64* __restrict__ khT, const u16* __restrict__ khW,
    ScanLds* L, int (&acc)[16], float (&racc)[16])
{
  const u32 cw = *(const u32*)&L->cntb[buf][0];
  if (cw != 0u){
    if (__builtin_expect((cw & 0x80808080u) == 0u, 1)){
      // sparse: per flagged wave, 4 padded slots, branch-free inner apply
      #pragma unroll
      for (int ww = 0; ww < 4; ++ww){
        if (((cw >> (8 * ww)) & 0xFFu) == 0u) continue;
        uint4 q = *(const uint4*)&L->seg[buf][ww][0];
        u32 evs[4] = {q.x, q.y, q.z, q.w};
        u32 bits[4];
        #pragma unroll
        for (int i = 0; i < 4; ++i)
          bits[i] = (u32)khW[((size_t)(evs[i] & 8191u) << 8) + tid];
        #pragma unroll
        for (int i = 0; i < 4; ++i){
          int sg = 1 - 2 * (int)((evs[i] >> 13) & 1u);
          #pragma unroll
          for (int j = 0; j < 16; ++j)
            acc[j] += sg * (int)((bits[i] >> j) & 1u);
        }
      }
    } else {
      // dense (t=0 onset / rare bursts)
      #pragma unroll 1
      for (int ww = 0; ww < 4; ++ww){
        u32 c = (cw >> (8 * ww)) & 0xFFu;
        if (c == 0u) continue;
        if (c == 0xFFu){
          #pragma unroll 1
          for (int j = 0; j < 16; ++j){
            int w2 = j * 4 + ww;
            u64 fp = L->fpos[buf][w2], fn = L->fneg[buf][w2];
            if (!(fp | fn)) continue;
            const u64* kp = khT + ((size_t)w2 << 12) + tid;
            #pragma unroll
            for (int jj = 0; jj < 16; ++jj){
              u64 k = kp[256 * jj];
              int tt = __popcll(fp & k) - __popcll(fn & k);
              acc[jj] += (w2 < 32) ? tt : -tt;
            }
          }
        } else {
          uint4 q = *(const uint4*)&L->seg[buf][ww][0];
          u32 evs[4] = {q.x, q.y, q.z, q.w};
          #pragma unroll
          for (int i = 0; i < 4; ++i){
            u32 bits = (u32)khW[((size_t)(evs[i] & 8191u) << 8) + tid];
            int sg = 1 - 2 * (int)((evs[i] >> 13) & 1u);
            #pragma unroll
            for (int j = 0; j < 16; ++j)
              acc[j] += sg * (int)((bits >> j) & 1u);
          }
        }
      }
    }
  }
  #pragma unroll
  for (int j = 0; j < 16; ++j) racc[j] = R_H * (float)acc[j];
}

__device__ __forceinline__ void snn_step(
    int t, int tid, int lane, int w, const u16* __restrict__ ip,
    const u64* __restrict__ khT, const u16* __restrict__ khW,
    u16 (&cur)[16],
    float (&v)[16], float (&isy)[16], float (&rate)[16], float (&rsum)[16],
    float (&racc)[16], int (&acc)[16], u32 &prevm,
    ScanLds* L)
{
  const int buf = t & 1;
  u32 snm = 0;
  #pragma unroll
  for (int j = 0; j < 16; ++j){
    isy[j] = fmaf(isy[j], A_SYN, racc[j]);
    float tv = fmaf(isy[j], BETA, b2f(cur[j]));   // beta*i_syn + beta*R_in*scale*(x@Kin)
    float vv = fmaf(v[j], A_VM, tv);
    bool sj = vv > 1.0f;
    v[j] = sj ? 0.0f : vv;
    rate[j] = fmaf(rate[j], A_VM, sj ? C_RATE : 0.0f);  // alpha_out == alpha_vm
    rsum[j] += rate[j];
    snm |= (u32)sj << j;
  }
  const u32 flm = snm ^ prevm;
  prevm = snm;
  const bool wany = __any(flm != 0);     // steady state: one ballot
  u64 bsp[16], bfl[16];
  if (wany){
    #pragma unroll
    for (int j = 0; j < 16; ++j){
      bsp[j] = __ballot((int)((snm >> j) & 1u));
      bfl[j] = __ballot((int)((flm >> j) & 1u));
    }
  }
  produce(lane, w, buf, bsp, bfl, wany, L);
  __syncthreads();
  // refill cur for t+2 AFTER the barrier (drains at NEXT barrier -> full step of slack)
  if (t + 2 < 256){
    const u16* qp = ip + (size_t)(t + 2) * 4096;
    #pragma unroll
    for (int j = 0; j < 16; ++j) cur[j] = qp[j * 256];
  }
  consume(tid, buf, khT, khW, L, acc, racc);
}

__global__ __launch_bounds__(256, 1) void snn_scan(
    const u16* __restrict__ iin, const u64* __restrict__ khT,
    const u16* __restrict__ khW,
    const float* __restrict__ v0, const float* __restrict__ is0,
    const float* __restrict__ r0, const int* __restrict__ s0,
    float* __restrict__ dout, float* __restrict__ rmean)
{
  const int b = blockIdx.x, tid = threadIdx.x;
  const int lane = tid & 63, w = tid >> 6;     // 4 waves
  __shared__ ScanLds L;

  float v[16], isy[16], rate[16], rsum[16], racc[16];
  int acc[16]; u32 prevm = 0;
  const size_t base = (size_t)b * 4096 + tid;  // neuron n = j*256 + tid
  const unsigned char* s0b = (const unsigned char*)s0;   // spike0 all-zero; byte-safe either layout
  #pragma unroll
  for (int j = 0; j < 16; ++j){
    v[j]    = v0 [base + j * 256];
    isy[j]  = is0[base + j * 256];
    rate[j] = r0 [base + j * 256];
    rsum[j] = 0.f;
    prevm |= (u32)(s0b[base + j * 256] != 0) << j;
    acc[j] = 0; racc[j] = 0.f;
  }

  { // init event (buf=1): flips = spike0 rising
    u64 bsp[16], bfl[16];
    bool wany = __any(prevm != 0);
    if (wany){
      #pragma unroll
      for (int j = 0; j < 16; ++j){
        bsp[j] = __ballot((int)((prevm >> j) & 1u));
        bfl[j] = bsp[j];
      }
    }
    produce(lane, w, 1, bsp, bfl, wany, &L);
    __syncthreads();
    consume(tid, 1, khT, khW, &L, acc, racc);
  }

  const u16* ip = iin + (size_t)b * 256 * 4096 + tid;
  u16 bufA[16], bufB[16];
  #pragma unroll
  for (int j = 0; j < 16; ++j) bufA[j] = ip[j * 256];
  #pragma unroll
  for (int j = 0; j < 16; ++j) bufB[j] = ip[4096 + j * 256];

  for (int t = 0; t < 256; t += 2){
    snn_step(t,     tid, lane, w, ip, khT, khW, bufA,
             v, isy, rate, rsum, racc, acc, prevm, &L);
    snn_step(t + 1, tid, lane, w, ip, khT, khW, bufB,
             v, isy, rate, rsum, racc, acc, prevm, &L);
  }

  #pragma unroll
  for (int j = 0; j < 16; ++j){
    size_t o = base + (size_t)j * 256;
    dout[o]           = v[j];
    dout[262144 + o]  = isy[j];
    dout[524288 + o]  = rate[j];
    dout[786432 + o]  = ((prevm >> j) & 1u) ? 1.0f : 0.0f;
    rmean[o] = rsum[j] * 0.00390625f;
  }
}

// ---------------- output head: R_out * rate_mean @ (kernel_out & exc_mask) ----------------
__global__ __launch_bounds__(256) void out_gemm(const float* __restrict__ rmean,
                                                const int* __restrict__ ko,
                                                const u32* __restrict__ flag,
                                                float* __restrict__ dout){
  const int b = blockIdx.x;
  const int o = blockIdx.y * 256 + threadIdx.x;
  const bool bm = (*flag) != 0;
  const unsigned char* kob = (const unsigned char*)ko;
  const float* rm = rmean + (size_t)b * 4096;
  float s = 0.f;
  #pragma unroll 8
  for (int n = 0; n < 2048; ++n){
    size_t idx = (size_t)n * 512 + o;
    int kv = bm ? (int)kob[idx] : ko[idx];
    s += rm[n] * (float)kv;
  }
  dout[1048576 + (size_t)b * 512 + o] = R_OUT * s;
}

extern "C" void kernel_launch(void* const* d_in, const int* in_sizes, int n_in,
                              void* d_out, int out_size, void* d_ws, size_t ws_size,
                              hipStream_t stream){
  (void)in_sizes; (void)n_in; (void)out_size; (void)ws_size;
  const float* x   = (const float*)d_in[0];
  const float* v0  = (const float*)d_in[1];
  const float* is0 = (const float*)d_in[2];
  const float* r0  = (const float*)d_in[3];
  const int*   s0  = (const int*)d_in[4];
  const int*   kin = (const int*)d_in[5];
  const int*   kh  = (const int*)d_in[6];
  const int*   ko  = (const int*)d_in[7];
  float* out = (float*)d_out;
  char* ws = (char*)d_ws;

  // rmean overlaps xb: xb is dead after gemm_iin, rmean written by snn_scan afterwards.
  u16*  xb    = (u16*)(ws);                       // [0, 33554432)
  float* rmean= (float*)(ws);                     // [0, 1048576)  lifetime-disjoint with xb
  float* sbeta= (float*)(ws + 33554432);          // 65,536 B
  u16*  iin   = (u16*)(ws + 33619968);            // 134,217,728 B
  u16*  Bt    = (u16*)(ws + 167837696);           // 8,388,608 B
  u64*  khT   = (u64*)(ws + 176226304);           // 2,097,152 B
  u16*  khW   = (u16*)(ws + 178323456);           // 2,097,664 B (4097 rows x 256 u16)
  u32*  flag  = (u32*)(ws + 180421632);           // 4 B

  hipMemsetAsync(flag, 0, 4, stream);
  detect_layout<<<dim3(1), dim3(256), 0, stream>>>((const u32*)kh, flag);
  prep_x<<<dim3(16384), dim3(256), 0, stream>>>(x, xb, sbeta);
  prep_bt<<<dim3(16, 64), dim3(256), 0, stream>>>(kin, flag, Bt);
  prep_kh<<<dim3(16, 64), dim3(256), 0, stream>>>(kh, flag, khT);
  prep_khW<<<dim3(4097), dim3(256), 0, stream>>>(kh, flag, khW);
  gemm_iin<<<dim3(128, 32), dim3(256), 0, stream>>>(xb, Bt, sbeta, iin);
  snn_scan<<<dim3(64), dim3(256), 0, stream>>>(iin, khT, khW, v0, is0, r0, s0, out, rmean);
  out_gemm<<<dim3(64, 2), dim3(256), 0, stream>>>(rmean, ko, flag, out);
}